// Round 8
// baseline (1527.213 us; speedup 1.0000x reference)
//
#include <hip/hip_runtime.h>

// Problem constants
#define BB    512
#define TT    300
#define DD    128
#define HH    256
#define GG    1024      // 4*H
#define DNS   256
#define NC    14
#define KDIM  76800     // T*H

typedef _Float16 f16;
typedef _Float16 f16x8 __attribute__((ext_vector_type(8)));
typedef float    f32x4 __attribute__((ext_vector_type(4)));
typedef unsigned long long u64;

__device__ __forceinline__ float sigf(float x){ return 1.0f / (1.0f + __expf(-x)); }
__device__ __forceinline__ float tanhfast(float x){ return 2.0f / (1.0f + __expf(-2.0f*x)) - 1.0f; }

// ---------------- K1: embedding gather, fp32 -> fp16 x[B][T][D] ----------------
__global__ void k_gather(const int* __restrict__ idx, const float* __restrict__ emb,
                         f16* __restrict__ xbuf)
{
    int gid = blockIdx.x * 256 + threadIdx.x;       // one 4-dim chunk
    if (gid >= BB*TT*DD/4) return;
    int bt = gid >> 5;                              // 32 chunks per 128-dim row
    int c4 = gid & 31;
    int v  = idx[bt];
    const float4 e = *(const float4*)(emb + (size_t)v*DD + c4*4);
    union { f16 h[4]; uint2 u; } o;
    o.h[0]=(f16)e.x; o.h[1]=(f16)e.y; o.h[2]=(f16)e.z; o.h[3]=(f16)e.w;
    *(uint2*)(xbuf + (size_t)bt*DD + c4*4) = o.u;
}

// ---------------- K2: persistent LSTM recurrence ----------------
// R15 = R13 (protocol proven correct, workspace-safe) with ONE change:
// __attribute__((amdgpu_waves_per_eu(4,4))) pins occupancy to exactly
// 4 waves/EU (1 block/CU for a 16-wave block) -> VGPR budget = 128.
// R12/R13's VGPR_Count=64 was the allocator targeting 8 waves/EU (max
// occupancy, 2 blocks/CU) and spilling bf[2][12] (96 regs) to scratch —
// launch_bounds' 2nd arg is only a MINIMUM waves/EU, so it couldn't
// prevent that. Live set ~115 <= 128 -> bf stays register-resident.
// Structure (unchanged): 64 blocks x 1024 thr = 32 batch-groups (16 rows)
// x 2 slots (128 h-dims = 512 gate rows); wave owns 2 n-tiles
// (bf[2][12] = 96 VGPR); M=16 full MFMA tiles.
// Exchange: tagged words ((t<<16)|f16), relaxed agent atomics, NO fences
// (R8 lesson), thread-paired ONE u64 publish / ONE u64 joint poll per
// thread (R9 lesson: joint not sequential). Depth-2 ping-pong race-free:
// producer reaches t+2 only after consuming h(t+1), which the peer
// publishes only after consuming h(t); publish(t-1) precedes poll(t-1)
// -> no deadlock. x_t load issued FIRST in the step so its HBM latency
// overlaps the poll wait.
__global__ __attribute__((amdgpu_waves_per_eu(4,4))) __launch_bounds__(1024)
void k_lstm(
    const f16* __restrict__ xbuf, f16* __restrict__ hs,
    const float* __restrict__ Wih, const float* __restrict__ Whh,
    const float* __restrict__ bih, const float* __restrict__ bhh,
    unsigned int* hpp)
{
    __shared__ f16   Ast[16*392];    // 16 rows x (256 h | 128 x | 8 pad)
    __shared__ float gbuf[16*516];   // gates [m][q], q = 4*d_local+ty, pad 516
    __shared__ float biasS[512];

    const int tid  = threadIdx.x;
    const int grp  = blockIdx.x & 31;               // batch-group: rows grp*16..+15
    const int slt  = blockIdx.x >> 5;               // slot 0..1 (same-XCD pairing)
    const int r0   = grp*16, j0 = slt*128;
    const int fb   = 128 - j0;                      // foreign slot dim base
    const int wv   = tid >> 6, lane = tid & 63;
    const int q16  = lane & 15, quad = lane >> 4;

    // ---- resident W fragments: wave wv owns n-tiles {2wv, 2wv+1} ----
    f16x8 bf[2][12];
    #pragma unroll
    for (int nt = 0; nt < 2; ++nt) {
        const int ql   = (wv*2 + nt)*16 + q16;      // local gate 0..511
        const int dl   = ql >> 2, ty = ql & 3;      // q = 4*d_local + ty
        const int Grow = ty*HH + j0 + dl;           // global gate row
        const float* wh = Whh + (size_t)Grow*HH;
        #pragma unroll
        for (int kk = 0; kk < 8; ++kk) {
            const float* p = wh + kk*32 + quad*8;
            float4 f0 = *(const float4*)p, f1 = *(const float4*)(p+4);
            f16x8 b;
            b[0]=(f16)f0.x; b[1]=(f16)f0.y; b[2]=(f16)f0.z; b[3]=(f16)f0.w;
            b[4]=(f16)f1.x; b[5]=(f16)f1.y; b[6]=(f16)f1.z; b[7]=(f16)f1.w;
            bf[nt][kk] = b;
        }
        const float* wi = Wih + (size_t)Grow*DD;
        #pragma unroll
        for (int kk = 0; kk < 4; ++kk) {
            const float* p = wi + kk*32 + quad*8;
            float4 f0 = *(const float4*)p, f1 = *(const float4*)(p+4);
            f16x8 b;
            b[0]=(f16)f0.x; b[1]=(f16)f0.y; b[2]=(f16)f0.z; b[3]=(f16)f0.w;
            b[4]=(f16)f1.x; b[5]=(f16)f1.y; b[6]=(f16)f1.z; b[7]=(f16)f1.w;
            bf[nt][8+kk] = b;
        }
    }
    if (tid < 512) {   // bias for local gate q = tid
        const int d = tid >> 2, ty = tid & 3;
        biasS[tid] = bih[ty*HH + j0 + d] + bhh[ty*HH + j0 + d];
    }

    // elementwise / exchange mapping: thread owns (row em, dims 2el, 2el+1)
    const int em = tid >> 6;                         // 0..15 (== wv)
    const int el = tid & 63;                         // 0..63
    float c0 = 0.f, c1 = 0.f;                        // cell state

    // zero-init h region of Ast (rows 0..15, dims 0..255); visible at syncA(t=0)
    {
        uint2 z = {0u,0u};
        *(uint2*)(Ast + (size_t)em*392 + el*4) = z;
    }

    const int xrow = tid >> 4, xch = tid & 15;       // x staging map (tid<256)

    for (int t = 0; t < TT; ++t) {
        // ---- issue x_t load FIRST (latency overlaps the poll below) ----
        uint4 xv;
        if (tid < 256)
            xv = *(const uint4*)(xbuf + ((size_t)(r0+xrow)*TT + t)*DD + xch*8);
        // ---- stage foreign h_{t-1}: joint poll of this thread's ONE u64 ----
        if (t > 0) {
            const unsigned tgt = (unsigned)(t-1);
            const u64* pb = (const u64*)(hpp + (size_t)((t-1)&1)*BB*HH
                                             + (size_t)(r0+em)*HH + fb + el*2);
            u64 v;
            for (;;) {
                v = __hip_atomic_load(pb, __ATOMIC_RELAXED, __HIP_MEMORY_SCOPE_AGENT);
                unsigned t0 = ((unsigned)(v >> 16)) & 0xFFFFu;
                unsigned t1 = (unsigned)(v >> 48);
                if ((t0==tgt) & (t1==tgt)) break;
                __builtin_amdgcn_s_sleep(1);
            }
            union { f16 h[2]; unsigned u; } fo;
            union { unsigned short us; f16 hf; } w0, w1;
            w0.us = (unsigned short)v;
            w1.us = (unsigned short)(v >> 32);
            fo.h[0]=w0.hf; fo.h[1]=w1.hf;
            *(unsigned*)(Ast + (size_t)em*392 + fb + el*2) = fo.u;
            // own 128 dims already in Ast (written by elementwise at t-1)
        }
        // ---- stage x_t (load issued above has drained by now) ----
        if (tid < 256)
            *(uint4*)(Ast + (size_t)xrow*392 + 256 + xch*8) = xv;
        __syncthreads();   // syncA: Ast complete (h 256 + x 128)

        // ---- gates[m][q] = sum_k A[m,k] * W[q,k]; wave = 2 n-tiles, M=16 ----
        f32x4 acc0 = {0.f,0.f,0.f,0.f}, acc1 = {0.f,0.f,0.f,0.f};
        const f16* arow = Ast + q16*392 + quad*8;
        #pragma unroll
        for (int kk = 0; kk < 12; ++kk) {
            f16x8 a = *(const f16x8*)(arow + kk*32);
            acc0 = __builtin_amdgcn_mfma_f32_16x16x32_f16(a, bf[0][kk], acc0, 0, 0, 0);
            acc1 = __builtin_amdgcn_mfma_f32_16x16x32_f16(a, bf[1][kk], acc1, 0, 0, 0);
        }
        // D layout: col=lane&15 -> q within tile, row=quad*4+r -> m
        #pragma unroll
        for (int r = 0; r < 4; ++r) {
            gbuf[(quad*4+r)*516 + (wv*2+0)*16 + q16] = acc0[r];
            gbuf[(quad*4+r)*516 + (wv*2+1)*16 + q16] = acc1[r];
        }
        __syncthreads();   // syncB: gates ready (all Ast reads of step t done)

        // ---- elementwise LSTM cell: (row em, dims 2el, 2el+1) ----
        const float* gb = gbuf  + (size_t)em*516 + el*8;
        const float* bb = biasS + el*8;
        union { f16 h[2]; unsigned u; } ho;
        unsigned pub0, pub1;
        {
            union { unsigned short us; f16 hf; } hu;
            float4 g, bs; float iv, fv, gv, ov, h;
            g = *(const float4*)(gb + 0);  bs = *(const float4*)(bb + 0);
            iv=sigf(g.x+bs.x); fv=sigf(g.y+bs.y); gv=tanhfast(g.z+bs.z); ov=sigf(g.w+bs.w);
            c0 = fv*c0 + iv*gv; h = ov*tanhfast(c0);
            hu.hf=(f16)h; ho.h[0]=hu.hf; pub0=((unsigned)t<<16)|hu.us;
            g = *(const float4*)(gb + 4);  bs = *(const float4*)(bb + 4);
            iv=sigf(g.x+bs.x); fv=sigf(g.y+bs.y); gv=tanhfast(g.z+bs.z); ov=sigf(g.w+bs.w);
            c1 = fv*c1 + iv*gv; h = ov*tanhfast(c1);
            hu.hf=(f16)h; ho.h[1]=hu.hf; pub1=((unsigned)t<<16)|hu.us;
        }
        // publish first (tagged words: validity travels with data), ONE u64
        u64* ob = (u64*)(hpp + (size_t)(t&1)*BB*HH + (size_t)(r0+em)*HH + j0 + el*2);
        u64 p01 = ((u64)pub1 << 32) | (u64)pub0;
        __hip_atomic_store(ob, p01, __ATOMIC_RELAXED, __HIP_MEMORY_SCOPE_AGENT);
        // own slice -> Ast for step t+1 (no fabric round-trip)
        *(unsigned*)(Ast + (size_t)em*392 + j0 + el*2) = ho.u;
        // hs for the dense layer: plain cached store, off the critical path
        *(unsigned*)(hs + ((size_t)(r0+em)*TT + t)*HH + j0 + el*2) = ho.u;
        // no third barrier: next step's Ast writes hit regions whose readers
        // finished before syncB; publishes are per-word self-validating.
    }
}

// ---------------- K3: dense GEMM, split-K -> partials ----------------
// A = hs (fp16), B = W3 (fp32, converted to fp16 during LDS staging -> no
// separate 236MB convert pass). dens[m][n] = sum_k hs[m,k]*W3[n,k].
__global__ __launch_bounds__(256) void k_dense(
    const f16* __restrict__ hs, const float* __restrict__ W3, float* __restrict__ part)
{
    __shared__ f16 Ap[128*40];
    __shared__ f16 Bp[128*40];
    const int tid = threadIdx.x;
    const int kb = blockIdx.x & 31, tn = (blockIdx.x >> 5) & 1, tm = blockIdx.x >> 6;
    const int m0 = tm*128, n0 = tn*128;
    const long k0 = (long)kb * 2400;
    const int wv = tid >> 6, lane = tid & 63, q16 = lane & 15, quad = lane >> 4;

    f32x4 acc[2][8];
    #pragma unroll
    for (int a = 0; a < 2; ++a)
        #pragma unroll
        for (int b = 0; b < 8; ++b) acc[a][b] = (f32x4){0.f,0.f,0.f,0.f};

    for (int ks = 0; ks < 75; ++ks) {
        const long kbase = k0 + ks*32;
        #pragma unroll
        for (int rep = 0; rep < 4; ++rep) {
            int cid = tid + rep*256;                 // 1024 chunks: 512 A + 512 B
            int rrow = (cid & 511) >> 2;
            int c4   = cid & 3;
            if (cid < 512) {
                const f16* src = hs + (size_t)(m0+rrow)*KDIM + kbase + c4*8;
                *(uint4*)(Ap + rrow*40 + c4*8) = *(const uint4*)src;
            } else {
                const float* src = W3 + (size_t)(n0+rrow)*KDIM + kbase + c4*8;
                float4 f0 = *(const float4*)src, f1 = *(const float4*)(src+4);
                union { f16 h[8]; uint4 u; } o;
                o.h[0]=(f16)f0.x; o.h[1]=(f16)f0.y; o.h[2]=(f16)f0.z; o.h[3]=(f16)f0.w;
                o.h[4]=(f16)f1.x; o.h[5]=(f16)f1.y; o.h[6]=(f16)f1.z; o.h[7]=(f16)f1.w;
                *(uint4*)(Bp + rrow*40 + c4*8) = o.u;
            }
        }
        __syncthreads();

        f16x8 a0 = *(const f16x8*)(Ap + ((wv*2+0)*16 + q16)*40 + quad*8);
        f16x8 a1 = *(const f16x8*)(Ap + ((wv*2+1)*16 + q16)*40 + quad*8);
        #pragma unroll
        for (int ns = 0; ns < 8; ++ns) {
            f16x8 b = *(const f16x8*)(Bp + (ns*16 + q16)*40 + quad*8);
            acc[0][ns] = __builtin_amdgcn_mfma_f32_16x16x32_f16(a0, b, acc[0][ns], 0,0,0);
            acc[1][ns] = __builtin_amdgcn_mfma_f32_16x16x32_f16(a1, b, acc[1][ns], 0,0,0);
        }
        __syncthreads();
    }
    #pragma unroll
    for (int ms = 0; ms < 2; ++ms)
        #pragma unroll
        for (int ns = 0; ns < 8; ++ns)
            #pragma unroll
            for (int r = 0; r < 4; ++r) {
                int m = m0 + (wv*2+ms)*16 + quad*4 + r;
                int n = n0 + ns*16 + q16;
                part[(size_t)kb*BB*DNS + (size_t)m*DNS + n] = acc[ms][ns][r];
            }
}

// ---------------- K4: reduce split-K partials + bias + relu ----------------
__global__ void k_reduce(const float* __restrict__ part, const float* __restrict__ b3,
                         float* __restrict__ dens)
{
    int g = blockIdx.x * 256 + threadIdx.x;
    if (g >= BB*DNS) return;
    int n = g & 255;
    float s = b3[n];
    #pragma unroll
    for (int kb = 0; kb < 32; ++kb) s += part[(size_t)kb*BB*DNS + g];
    dens[g] = fmaxf(s, 0.0f);
}

// ---------------- K5: final 256->14 + softmax ----------------
__global__ __launch_bounds__(64) void k_final(
    const float* __restrict__ dens, const float* __restrict__ W4,
    const float* __restrict__ b4, float* __restrict__ out)
{
    const int b = blockIdx.x, lane = threadIdx.x;
    const float4 dv = *(const float4*)(dens + (size_t)b*DNS + lane*4);
    float lg[NC];
    #pragma unroll
    for (int cc = 0; cc < NC; ++cc) {
        const float4 w = *(const float4*)(W4 + (size_t)cc*DNS + lane*4);
        float v = dv.x*w.x + dv.y*w.y + dv.z*w.z + dv.w*w.w;
        #pragma unroll
        for (int off = 32; off; off >>= 1) v += __shfl_xor(v, off, 64);
        lg[cc] = v + b4[cc];
    }
    if (lane == 0) {
        float m = lg[0];
        #pragma unroll
        for (int cc = 1; cc < NC; ++cc) m = fmaxf(m, lg[cc]);
        float e[NC], s = 0.f;
        #pragma unroll
        for (int cc = 0; cc < NC; ++cc) { e[cc] = __expf(lg[cc]-m); s += e[cc]; }
        const float inv = 1.0f/s;
        #pragma unroll
        for (int cc = 0; cc < NC; ++cc) out[(size_t)b*NC + cc] = e[cc]*inv;
    }
}

// ---------------- launch ----------------
extern "C" void kernel_launch(void* const* d_in, const int* in_sizes, int n_in,
                              void* d_out, int out_size, void* d_ws, size_t ws_size,
                              hipStream_t stream)
{
    const int*   idx = (const int*)  d_in[0];
    // d_in[1] = traj_lens: unused by the reference
    const float* emb = (const float*)d_in[2];
    const float* Wih = (const float*)d_in[3];
    const float* Whh = (const float*)d_in[4];
    const float* bih = (const float*)d_in[5];
    const float* bhh = (const float*)d_in[6];
    const float* W3  = (const float*)d_in[7];
    const float* b3  = (const float*)d_in[8];
    const float* W4  = (const float*)d_in[9];
    const float* b4  = (const float*)d_in[10];
    float* out = (float*)d_out;

    char* ws = (char*)d_ws;
    f16*   xbuf = (f16*)  (ws);                           // 39,321,600 B
    f16*   hs   = (f16*)  (ws + 39321600);                // 78,643,200 B
    float* part = (float*)(ws + 117964800);               // 16,777,216 B
    float* dens = (float*)(ws + 134742016);               //    524,288 B
    // Footprint 135.27 MB — matches the proven champion layout exactly
    // (ws_size has no headroom beyond it; R14's 198 MB layout crashed).
    // hpp (tagged h ping-pong, 2x512x256 u32 = 1 MB) aliases `part`:
    // used only during k_lstm; part written only afterwards by k_dense.
    // Tags self-validate against stale/poison data -> no memset needed.
    unsigned int* hpp = (unsigned int*)part;

    k_gather<<<19200, 256, 0, stream>>>(idx, emb, xbuf);
    k_lstm  <<<64, 1024, 0, stream>>>(xbuf, hs, Wih, Whh, bih, bhh, hpp);
    k_dense <<<256, 256, 0, stream>>>(hs, W3, part);
    k_reduce<<<512, 256, 0, stream>>>(part, b3, dens);
    k_final <<<BB, 64, 0, stream>>>(dens, W4, b4, out);
}

// Round 9
// 759.789 us; speedup vs baseline: 2.0100x; 2.0100x over previous
//
#include <hip/hip_runtime.h>

// Problem constants
#define BB    512
#define TT    300
#define DD    128
#define HH    256
#define GG    1024      // 4*H
#define DNS   256
#define NC    14
#define KDIM  76800     // T*H

typedef _Float16 f16;
typedef _Float16 f16x8 __attribute__((ext_vector_type(8)));
typedef float    f32x4 __attribute__((ext_vector_type(4)));

__device__ __forceinline__ float sigf(float x){ return 1.0f / (1.0f + __expf(-x)); }
__device__ __forceinline__ float tanhfast(float x){ return 2.0f / (1.0f + __expf(-2.0f*x)) - 1.0f; }

// ---------------- K1: embedding gather, fp32 -> fp16 x[B][T][D] ----------------
__global__ void k_gather(const int* __restrict__ idx, const float* __restrict__ emb,
                         f16* __restrict__ xbuf)
{
    int gid = blockIdx.x * 256 + threadIdx.x;       // one 4-dim chunk
    if (gid >= BB*TT*DD/4) return;
    int bt = gid >> 5;                              // 32 chunks per 128-dim row
    int c4 = gid & 31;
    int v  = idx[bt];
    const float4 e = *(const float4*)(emb + (size_t)v*DD + c4*4);
    union { f16 h[4]; uint2 u; } o;
    o.h[0]=(f16)e.x; o.h[1]=(f16)e.y; o.h[2]=(f16)e.z; o.h[3]=(f16)e.w;
    *(uint2*)(xbuf + (size_t)bt*DD + c4*4) = o.u;
}

// ---------------- K2: persistent LSTM recurrence ----------------
// R16 = CHAMPION structure (256 blocks x 512 thr, degree-3 exchange, VGPR
// ~108 — the only config the allocator honors; R10-R15 proved 1024-thr and
// near-cap-VGPR variants get demoted to 64 + scratch) with a split-barrier
// overlap: the Ast h-layout is ROTATED by j0 (own 64 dims -> positions
// 0..63), making the K-fragment split static:
//   phase A = {own-h kk 0,1; x kk 8..11}  — needs NO foreign data
//   phase B = {foreign-h kk 2..7}
// Step: stage x (register-prefetched) -> syncA1 -> phase-A MFMAs -> POLL
// (champion's exact 3-word joint tagged poll) -> syncA2 -> phase-B MFMAs ->
// gbuf -> syncB -> elementwise/publish. The publish->visible fabric flight
// now overlaps x-stage + barrier + 12 MFMAs instead of nothing.
// Whh fragment columns are loaded with the same mod-256 rotation.
// Exchange protocol BYTE-IDENTICAL to the 665us champion: tagged words
// ((t<<16)|f16), relaxed agent atomics, NO fences (R8 lesson), joint poll
// (R9 lesson), depth-2 ping-pong (producer reaches t+2 only after consuming
// h(t+1), which peers publish only after consuming h(t)).
// Race audit (rotated layout): x writes(t) < syncA1(t), x reads(t-1) <
// syncA2(t-1) < syncB(t-1) < x writes(t). Foreign writes(t) in (syncA1,
// syncA2), foreign reads(t-1) < syncB(t-1) < syncA1(t). Own writes(end t-1)
// < syncA1(t) < own reads(t). gbuf writes(t) > syncA2(t) > elementwise
// reads(t-1). All ordered.
__global__ __launch_bounds__(512) void k_lstm(
    const f16* __restrict__ xbuf, f16* __restrict__ hs,
    const float* __restrict__ Wih, const float* __restrict__ Whh,
    const float* __restrict__ bih, const float* __restrict__ bhh,
    unsigned int* hpp)
{
    __shared__ f16   Ast[16*392];    // 16 rows (8 real) x (256 h-rot | 128 x | 8 pad)
    __shared__ float gbuf[16*260];   // gates [m][q], q = 4*d+ty, pad 260
    __shared__ float biasS[256];

    const int tid  = threadIdx.x;
    const int bsI  = blockIdx.x & 63;               // batch-slice (group id)
    const int sI   = blockIdx.x >> 6;               // slot 0..3 (same-XCD swizzle)
    const int r0   = bsI*8, j0 = sI*64;
    const int wv   = tid >> 6, lane = tid & 63;
    const int q16  = lane & 15, quad = lane >> 4;

    // ---- resident W fragments: wave wv owns n-tiles {2wv, 2wv+1} ----
    // Whh K-columns rotated by j0 (position p holds global dim (p+j0)&255).
    f16x8 bf[2][12];
    #pragma unroll
    for (int nt = 0; nt < 2; ++nt) {
        const int ql   = (wv*2 + nt)*16 + q16;      // local gate 0..255
        const int drow = ql >> 2, ty = ql & 3;      // q = 4*d + ty
        const int Grow = ty*HH + j0 + drow;         // global gate row
        const float* wh = Whh + (size_t)Grow*HH;
        #pragma unroll
        for (int kk = 0; kk < 8; ++kk) {
            const int col = ((kk*32 + j0) & 255) + quad*8;   // rotated column
            const float* p = wh + col;
            float4 f0 = *(const float4*)p, f1 = *(const float4*)(p+4);
            f16x8 b;
            b[0]=(f16)f0.x; b[1]=(f16)f0.y; b[2]=(f16)f0.z; b[3]=(f16)f0.w;
            b[4]=(f16)f1.x; b[5]=(f16)f1.y; b[6]=(f16)f1.z; b[7]=(f16)f1.w;
            bf[nt][kk] = b;
        }
        const float* wi = Wih + (size_t)Grow*DD;
        #pragma unroll
        for (int kk = 0; kk < 4; ++kk) {
            const float* p = wi + kk*32 + quad*8;
            float4 f0 = *(const float4*)p, f1 = *(const float4*)(p+4);
            f16x8 b;
            b[0]=(f16)f0.x; b[1]=(f16)f0.y; b[2]=(f16)f0.z; b[3]=(f16)f0.w;
            b[4]=(f16)f1.x; b[5]=(f16)f1.y; b[6]=(f16)f1.z; b[7]=(f16)f1.w;
            bf[nt][8+kk] = b;
        }
    }
    if (tid < 256) {
        const int drow = tid >> 2, ty = tid & 3;
        const int Grow = ty*HH + j0 + drow;
        biasS[tid] = bih[Grow] + bhh[Grow];
    }

    float c = 0.0f;                                  // cell state: (row wv, dim lane)
    // this lane's 3 foreign words of row wv: fd = lane*3 + i (192 = 64 lanes x 3)
    const int f0 = lane*3;
    const int d0 = (f0   < j0) ? f0   : f0+64;       // global dims (hpp addressing)
    const int d1 = (f0+1 < j0) ? f0+1 : f0+1+64;
    const int d2 = (f0+2 < j0) ? f0+2 : f0+2+64;
    const int p0 = (d0 - j0) & 255;                  // rotated Ast positions 64..255
    const int p1 = (d1 - j0) & 255;
    const int p2 = (d2 - j0) & 255;

    // zero-init h region of real rows (0..7), all 256 positions
    if (tid < 256) {
        const int row = tid >> 5;
        uint4 z = {0u,0u,0u,0u};
        *(uint4*)(Ast + (size_t)row*392 + (tid & 31)*8) = z;
    }

    // x prefetch (tid<128): x(t) resident in registers before step t starts
    const int xrow = tid >> 4, xch = tid & 15;
    uint4 xreg;
    if (tid < 128)
        xreg = *(const uint4*)(xbuf + ((size_t)(r0+xrow)*TT + 0)*DD + xch*8);

    for (int t = 0; t < TT; ++t) {
        // ---- stage x_t from registers (zero latency), prefetch x_{t+1} ----
        if (tid < 128) {
            *(uint4*)(Ast + (size_t)xrow*392 + 256 + xch*8) = xreg;
            if (t + 1 < TT)
                xreg = *(const uint4*)(xbuf + ((size_t)(r0+xrow)*TT + (t+1))*DD + xch*8);
        }
        __syncthreads();   // syncA1: x + own-h (+t=0 zeros) ready

        // ---- phase A MFMAs: own-h (kk 0,1) + x (kk 8..11) ----
        f32x4 acc0 = {0.f,0.f,0.f,0.f}, acc1 = {0.f,0.f,0.f,0.f};
        const f16* arow = Ast + q16*392 + quad*8;
        {
            f16x8 a;
            a = *(const f16x8*)(arow + 0*32);
            acc0 = __builtin_amdgcn_mfma_f32_16x16x32_f16(a, bf[0][0], acc0, 0, 0, 0);
            acc1 = __builtin_amdgcn_mfma_f32_16x16x32_f16(a, bf[1][0], acc1, 0, 0, 0);
            a = *(const f16x8*)(arow + 1*32);
            acc0 = __builtin_amdgcn_mfma_f32_16x16x32_f16(a, bf[0][1], acc0, 0, 0, 0);
            acc1 = __builtin_amdgcn_mfma_f32_16x16x32_f16(a, bf[1][1], acc1, 0, 0, 0);
            #pragma unroll
            for (int kk = 8; kk < 12; ++kk) {
                a = *(const f16x8*)(arow + kk*32);
                acc0 = __builtin_amdgcn_mfma_f32_16x16x32_f16(a, bf[0][kk], acc0, 0, 0, 0);
                acc1 = __builtin_amdgcn_mfma_f32_16x16x32_f16(a, bf[1][kk], acc1, 0, 0, 0);
            }
        }

        // ---- poll foreign h_{t-1}: champion's joint tagged 3-word poll ----
        if (t > 0) {
            unsigned int* pb = hpp + (size_t)((t-1)&1)*BB*HH + (size_t)(r0+wv)*HH;
            const unsigned int tgt = (unsigned)(t-1);
            unsigned int v0, v1, v2;
            for (;;) {
                v0 = __hip_atomic_load(pb+d0, __ATOMIC_RELAXED, __HIP_MEMORY_SCOPE_AGENT);
                v1 = __hip_atomic_load(pb+d1, __ATOMIC_RELAXED, __HIP_MEMORY_SCOPE_AGENT);
                v2 = __hip_atomic_load(pb+d2, __ATOMIC_RELAXED, __HIP_MEMORY_SCOPE_AGENT);
                if (((v0>>16)==tgt) & ((v1>>16)==tgt) & ((v2>>16)==tgt)) break;
                __builtin_amdgcn_s_sleep(1);
            }
            union { unsigned short us; f16 hf; } u0, u1, u2;
            u0.us = (unsigned short)v0; u1.us = (unsigned short)v1; u2.us = (unsigned short)v2;
            Ast[wv*392 + p0] = u0.hf;
            Ast[wv*392 + p1] = u1.hf;
            Ast[wv*392 + p2] = u2.hf;
            // own 64 dims (positions 0..63) written by elementwise at t-1
        }
        __syncthreads();   // syncA2: foreign h ready

        // ---- phase B MFMAs: foreign-h (kk 2..7) ----
        #pragma unroll
        for (int kk = 2; kk < 8; ++kk) {
            f16x8 a = *(const f16x8*)(arow + kk*32);
            acc0 = __builtin_amdgcn_mfma_f32_16x16x32_f16(a, bf[0][kk], acc0, 0, 0, 0);
            acc1 = __builtin_amdgcn_mfma_f32_16x16x32_f16(a, bf[1][kk], acc1, 0, 0, 0);
        }
        // D layout: col=lane&15 -> q within tile, row=quad*4+r -> m
        #pragma unroll
        for (int r = 0; r < 4; ++r) {
            gbuf[(quad*4+r)*260 + (wv*2+0)*16 + q16] = acc0[r];
            gbuf[(quad*4+r)*260 + (wv*2+1)*16 + q16] = acc1[r];
        }
        __syncthreads();   // syncB: gates ready (all Ast reads of step t done)

        // ---- elementwise LSTM cell: (row wv, dim lane) ----
        float h;
        {
            const float4 g = *(const float4*)(gbuf + wv*260 + lane*4);
            const float4 bs = *(const float4*)(biasS + lane*4);
            float gi = g.x + bs.x;
            float gf = g.y + bs.y;
            float gg = g.z + bs.z;
            float go = g.w + bs.w;
            float iv = sigf(gi), fv = sigf(gf), gv = tanhfast(gg), ov = sigf(go);
            c = fv*c + iv*gv;
            h = ov * tanhfast(c);
        }
        union { unsigned short us; f16 hf; } cv; cv.hf = (f16)h;
        // publish first (tagged word: validity travels with data, per-lane dword)
        __hip_atomic_store(hpp + (size_t)(t&1)*BB*HH + (size_t)(r0+wv)*HH + j0 + lane,
                           ((unsigned)t << 16) | cv.us,
                           __ATOMIC_RELAXED, __HIP_MEMORY_SCOPE_AGENT);
        // own slice -> Ast position `lane` (rotated layout) for step t+1
        Ast[wv*392 + lane] = cv.hf;
        // hs for the dense layer: plain cached store, off the critical path
        hs[((size_t)(r0+wv)*TT + t)*HH + j0 + lane] = cv.hf;
        // next step's Ast writes (x, foreign) are barrier-ordered vs this
        // step's readers (see race audit in header comment).
    }
}

// ---------------- K3: dense GEMM, split-K -> partials ----------------
// A = hs (fp16), B = W3 (fp32, converted to fp16 during LDS staging -> no
// separate 236MB convert pass). dens[m][n] = sum_k hs[m,k]*W3[n,k].
__global__ __launch_bounds__(256) void k_dense(
    const f16* __restrict__ hs, const float* __restrict__ W3, float* __restrict__ part)
{
    __shared__ f16 Ap[128*40];
    __shared__ f16 Bp[128*40];
    const int tid = threadIdx.x;
    const int kb = blockIdx.x & 31, tn = (blockIdx.x >> 5) & 1, tm = blockIdx.x >> 6;
    const int m0 = tm*128, n0 = tn*128;
    const long k0 = (long)kb * 2400;
    const int wv = tid >> 6, lane = tid & 63, q16 = lane & 15, quad = lane >> 4;

    f32x4 acc[2][8];
    #pragma unroll
    for (int a = 0; a < 2; ++a)
        #pragma unroll
        for (int b = 0; b < 8; ++b) acc[a][b] = (f32x4){0.f,0.f,0.f,0.f};

    for (int ks = 0; ks < 75; ++ks) {
        const long kbase = k0 + ks*32;
        #pragma unroll
        for (int rep = 0; rep < 4; ++rep) {
            int cid = tid + rep*256;                 // 1024 chunks: 512 A + 512 B
            int rrow = (cid & 511) >> 2;
            int c4   = cid & 3;
            if (cid < 512) {
                const f16* src = hs + (size_t)(m0+rrow)*KDIM + kbase + c4*8;
                *(uint4*)(Ap + rrow*40 + c4*8) = *(const uint4*)src;
            } else {
                const float* src = W3 + (size_t)(n0+rrow)*KDIM + kbase + c4*8;
                float4 f0 = *(const float4*)src, f1 = *(const float4*)(src+4);
                union { f16 h[8]; uint4 u; } o;
                o.h[0]=(f16)f0.x; o.h[1]=(f16)f0.y; o.h[2]=(f16)f0.z; o.h[3]=(f16)f0.w;
                o.h[4]=(f16)f1.x; o.h[5]=(f16)f1.y; o.h[6]=(f16)f1.z; o.h[7]=(f16)f1.w;
                *(uint4*)(Bp + rrow*40 + c4*8) = o.u;
            }
        }
        __syncthreads();

        f16x8 a0 = *(const f16x8*)(Ap + ((wv*2+0)*16 + q16)*40 + quad*8);
        f16x8 a1 = *(const f16x8*)(Ap + ((wv*2+1)*16 + q16)*40 + quad*8);
        #pragma unroll
        for (int ns = 0; ns < 8; ++ns) {
            f16x8 b = *(const f16x8*)(Bp + (ns*16 + q16)*40 + quad*8);
            acc[0][ns] = __builtin_amdgcn_mfma_f32_16x16x32_f16(a0, b, acc[0][ns], 0,0,0);
            acc[1][ns] = __builtin_amdgcn_mfma_f32_16x16x32_f16(a1, b, acc[1][ns], 0,0,0);
        }
        __syncthreads();
    }
    #pragma unroll
    for (int ms = 0; ms < 2; ++ms)
        #pragma unroll
        for (int ns = 0; ns < 8; ++ns)
            #pragma unroll
            for (int r = 0; r < 4; ++r) {
                int m = m0 + (wv*2+ms)*16 + quad*4 + r;
                int n = n0 + ns*16 + q16;
                part[(size_t)kb*BB*DNS + (size_t)m*DNS + n] = acc[ms][ns][r];
            }
}

// ---------------- K4: reduce split-K partials + bias + relu ----------------
__global__ void k_reduce(const float* __restrict__ part, const float* __restrict__ b3,
                         float* __restrict__ dens)
{
    int g = blockIdx.x * 256 + threadIdx.x;
    if (g >= BB*DNS) return;
    int n = g & 255;
    float s = b3[n];
    #pragma unroll
    for (int kb = 0; kb < 32; ++kb) s += part[(size_t)kb*BB*DNS + g];
    dens[g] = fmaxf(s, 0.0f);
}

// ---------------- K5: final 256->14 + softmax ----------------
__global__ __launch_bounds__(64) void k_final(
    const float* __restrict__ dens, const float* __restrict__ W4,
    const float* __restrict__ b4, float* __restrict__ out)
{
    const int b = blockIdx.x, lane = threadIdx.x;
    const float4 dv = *(const float4*)(dens + (size_t)b*DNS + lane*4);
    float lg[NC];
    #pragma unroll
    for (int cc = 0; cc < NC; ++cc) {
        const float4 w = *(const float4*)(W4 + (size_t)cc*DNS + lane*4);
        float v = dv.x*w.x + dv.y*w.y + dv.z*w.z + dv.w*w.w;
        #pragma unroll
        for (int off = 32; off; off >>= 1) v += __shfl_xor(v, off, 64);
        lg[cc] = v + b4[cc];
    }
    if (lane == 0) {
        float m = lg[0];
        #pragma unroll
        for (int cc = 1; cc < NC; ++cc) m = fmaxf(m, lg[cc]);
        float e[NC], s = 0.f;
        #pragma unroll
        for (int cc = 0; cc < NC; ++cc) { e[cc] = __expf(lg[cc]-m); s += e[cc]; }
        const float inv = 1.0f/s;
        #pragma unroll
        for (int cc = 0; cc < NC; ++cc) out[(size_t)b*NC + cc] = e[cc]*inv;
    }
}

// ---------------- launch ----------------
extern "C" void kernel_launch(void* const* d_in, const int* in_sizes, int n_in,
                              void* d_out, int out_size, void* d_ws, size_t ws_size,
                              hipStream_t stream)
{
    const int*   idx = (const int*)  d_in[0];
    // d_in[1] = traj_lens: unused by the reference
    const float* emb = (const float*)d_in[2];
    const float* Wih = (const float*)d_in[3];
    const float* Whh = (const float*)d_in[4];
    const float* bih = (const float*)d_in[5];
    const float* bhh = (const float*)d_in[6];
    const float* W3  = (const float*)d_in[7];
    const float* b3  = (const float*)d_in[8];
    const float* W4  = (const float*)d_in[9];
    const float* b4  = (const float*)d_in[10];
    float* out = (float*)d_out;

    char* ws = (char*)d_ws;
    f16*   xbuf = (f16*)  (ws);                           // 39,321,600 B
    f16*   hs   = (f16*)  (ws + 39321600);                // 78,643,200 B
    float* part = (float*)(ws + 117964800);               // 16,777,216 B
    float* dens = (float*)(ws + 134742016);               //    524,288 B
    // Footprint 135.27 MB — the proven champion layout (no headroom beyond).
    // hpp (tagged h ping-pong, 2x512x256 uint32 = 1 MB) aliases `part`:
    // used only during k_lstm; part written only afterwards by k_dense.
    // Tags self-validate against stale/poison data -> no memset needed.
    unsigned int* hpp = (unsigned int*)part;

    k_gather<<<19200, 256, 0, stream>>>(idx, emb, xbuf);
    k_lstm  <<<256, 512, 0, stream>>>(xbuf, hs, Wih, Whh, bih, bhh, hpp);
    k_dense <<<256, 256, 0, stream>>>(hs, W3, part);
    k_reduce<<<512, 256, 0, stream>>>(part, b3, dens);
    k_final <<<BB, 64, 0, stream>>>(dens, W4, b4, out);
}